// Round 10
// baseline (190.302 us; speedup 1.0000x reference)
//
#include <hip/hip_runtime.h>
#include <hip/hip_bf16.h>
#include <math.h>

#define BQ   2      // batch
#define NN   1024   // seq len
#define DMD  512    // d_model
#define NH   8      // heads
#define DKK  64     // head dim
#define NSEL 5      // NB+1 block values (0..4)
#define NCLS 17     // block-pair classes
#define NP   1280   // padded per-batch capacity: nTot = sum(ceil(c_i/64)*64) <= 1339 and %64==0 -> <=1280
#define NPT  20     // NP/64 tiles
#define MAXT 3      // max key-tiles per wave in k_attn (ceil(20/8))
#define SSp  1284   // S row stride (shorts): 2568B = 642 words == 2 mod 32 banks, conflict-free shift
#define QLS  68     // qloc/u row stride (shorts)

typedef __attribute__((ext_vector_type(8))) short bf16x8;
typedef __attribute__((ext_vector_type(8))) unsigned short u16x8;
typedef __attribute__((ext_vector_type(4))) float f32x4;

__device__ __forceinline__ int clsOf(int r, int c) { return (r == 0 || c == 0) ? 0 : ((r - 1) * 4 + c); }

__device__ __forceinline__ unsigned short f2bf(float x) {
    __hip_bfloat16 h = __float2bfloat16(x);
    return *reinterpret_cast<unsigned short*>(&h);
}

__device__ __forceinline__ float bf2f(unsigned short v) {
    unsigned int u = ((unsigned int)v) << 16;
    float f;
    __builtin_memcpy(&f, &u, 4);
    return f;
}

// ---------------------------------------------------------------- prep: lin cast (960) + qkv cast (96) + setup (1)
__global__ __launch_bounds__(256) void k_prep(
    const float* __restrict__ lr, unsigned short* __restrict__ Lt,
    const float* __restrict__ qr, const float* __restrict__ kr, const float* __restrict__ vr,
    unsigned short* __restrict__ Xc,
    const void* __restrict__ b_seq_r, const void* __restrict__ mask_r,
    int* __restrict__ maskI, int* __restrict__ perm, int* __restrict__ rowc,
    int* __restrict__ startPad, int* __restrict__ maskP)
{
    __shared__ float Tf[64][68];
    __shared__ int det[5];
    __shared__ int cnts[BQ][NSEL];
    __shared__ int offs[BQ][NSEL];
    __shared__ int sstart[BQ][NSEL + 1];
    int bx = blockIdx.x;
    int tid = threadIdx.x;
    if (bx < 960) {
        // cast+transpose lin[ts][k][n] -> Lt[ts][n][k] bf16
        int ts = bx >> 6, rem = bx & 63;
        int kt = rem >> 3, nt = rem & 7;
        const float* src = lr + (size_t)ts * DMD * 512;
        unsigned short* dst = Lt + (size_t)ts * DMD * 512;
        int r = tid >> 2, c4 = tid & 3;
#pragma unroll
        for (int i = 0; i < 4; i++) {
            float4 v = *(const float4*)&src[(size_t)(kt * 64 + r) * 512 + nt * 64 + c4 * 16 + i * 4];
            *(float4*)&Tf[r][c4 * 16 + i * 4] = v;
        }
        __syncthreads();
        unsigned short tmp[16];
#pragma unroll
        for (int i = 0; i < 16; i++) tmp[i] = f2bf(Tf[c4 * 16 + i][r]);
        u16x8 o0, o1;
#pragma unroll
        for (int i = 0; i < 8; i++) { o0[i] = tmp[i]; o1[i] = tmp[8 + i]; }
        unsigned short* dp = &dst[(size_t)(nt * 64 + r) * 512 + kt * 64 + c4 * 16];
        *(u16x8*)&dp[0] = o0;
        *(u16x8*)&dp[8] = o1;
    } else if (bx < 960 + 96) {
        // cast q/k/v -> Xc bf16 [t][b][n][512]
        int bid = bx - 960;                     // 0..95
        int t = bid / 32, rem = bid % 32;
        int b = rem / 16, rg = rem % 16;
        int row = tid >> 2, part = tid & 3;
        const float* X = (t == 0) ? qr : ((t == 1) ? kr : vr);
        const float* src = X + ((size_t)b * NN + rg * 64 + row) * DMD + part * 128;
        unsigned short* dst = Xc + (((size_t)t * BQ + b) * NN + rg * 64 + row) * DMD + part * 128;
#pragma unroll
        for (int i = 0; i < 128; i += 8) {
            float4 v0 = *(const float4*)&src[i];
            float4 v1 = *(const float4*)&src[i + 4];
            u16x8 o;
            o[0] = f2bf(v0.x); o[1] = f2bf(v0.y); o[2] = f2bf(v0.z); o[3] = f2bf(v0.w);
            o[4] = f2bf(v1.x); o[5] = f2bf(v1.y); o[6] = f2bf(v1.z); o[7] = f2bf(v1.w);
            *(u16x8*)&dst[i] = o;
        }
    } else {
        // ---- setup (single block): dtype detect, bucketize, perm, masks
        if (tid < 5) det[tid] = 0;
        if (tid < BQ * NSEL) { cnts[tid / NSEL][tid % NSEL] = 0; offs[tid / NSEL][tid % NSEL] = 0; }
        __syncthreads();
        const int* b32 = (const int*)b_seq_r;
        const unsigned char* mb = (const unsigned char*)mask_r;
        const int* m32 = (const int*)mask_r;
        if (tid < 64) {
            if (b32[2 * tid + 1] != 0) atomicOr(&det[0], 1);
            if (b32[2 * tid] != 0)     atomicOr(&det[1], 1);
            if (m32[2 * tid + 1] != 0) atomicOr(&det[3], 1);
            if (m32[2 * tid] != 0)     atomicOr(&det[4], 1);
        }
        if ((tid & 3) != 0 && mb[tid] != 0) atomicOr(&det[2], 1);
        __syncthreads();
        int bsI64 = (det[0] == 0 && det[1] != 0);
        int mk = det[2] ? 1 : ((det[3] == 0 && det[4] != 0) ? 2 : 0);

        for (int g = tid; g < BQ * NN; g += 256) {
            int m = (mk == 1) ? (mb[g] != 0) : ((mk == 2) ? (m32[2 * g] != 0) : (m32[g] != 0));
            maskI[g] = m;
            int bs = bsI64 ? b32[2 * g] : b32[g];
            bs = bs < 0 ? 0 : (bs > 4 ? 4 : bs);
            atomicAdd(&cnts[g / NN][bs], 1);
        }
        __syncthreads();
        if (tid == 0) {
            for (int b = 0; b < BQ; b++) {
                int acc = 0;
                for (int c = 0; c < NSEL; c++) {
                    sstart[b][c] = acc;
                    acc += ((cnts[b][c] + 63) / 64) * 64;
                }
                sstart[b][NSEL] = acc;
                for (int c = 0; c <= NSEL; c++) startPad[b * (NSEL + 1) + c] = sstart[b][c];
            }
        }
        __syncthreads();
        for (int g = tid; g < BQ * NP; g += 256) {
            perm[g] = -1;
            int b = g / NP, sslot = g % NP;
            int c = 0;
            for (int cc = 1; cc < NSEL; cc++) if (sslot >= sstart[b][cc]) c = cc;
            rowc[g] = c;
        }
        __syncthreads();
        for (int g = tid; g < BQ * NN; g += 256) {
            int b = g / NN, n = g % NN;
            int bs = bsI64 ? b32[2 * g] : b32[g];
            bs = bs < 0 ? 0 : (bs > 4 ? 4 : bs);
            int pos = sstart[b][bs] + atomicAdd(&offs[b][bs], 1);
            perm[b * NP + pos] = n;
        }
        __syncthreads();
        for (int g = tid; g < BQ * NP; g += 256) {
            int tok = perm[g];
            maskP[g] = (tok < 0) ? 2 : maskI[(g / NP) * NN + tok];
        }
    }
}

// ---------------------------------------------------------------- QKV projection (960 blocks) + wmix (272 blocks)
__global__ __launch_bounds__(256) void k_proj(
    const unsigned short* __restrict__ Xc,
    const unsigned short* __restrict__ Lt,
    const int* __restrict__ perm, const int* __restrict__ rowc, const int* __restrict__ startPad,
    unsigned short* __restrict__ Qb, unsigned short* __restrict__ Kb,
    unsigned short* __restrict__ Vt,
    const float* __restrict__ W1, const float* __restrict__ W2,
    const float* __restrict__ al1, const float* __restrict__ al2,
    unsigned short* __restrict__ W1bt, unsigned short* __restrict__ W2bt)
{
    __shared__ __align__(16) unsigned short Xb[64][72];
    __shared__ __align__(16) unsigned short Lb[64][72];
    __shared__ int toks[64];

    int bid = blockIdx.x;
    int tid = threadIdx.x;
    if (bid >= 960) {
        // ---- wmix: W1m/W2m mixtures, transposed bf16
        int bid2 = bid - 960;
        int w = bid2 / (NCLS * NH);
        int rem = bid2 % (NCLS * NH);
        int c = rem / NH, h = rem % NH;
        const float* W = w ? W2 : W1;
        const float* a = w ? al2 : al1;
        unsigned short* outp = (w ? W2bt : W1bt) + (((size_t)c * NH + h) << 12);
        float vals[4], mx = -1e30f;
#pragma unroll
        for (int bb = 0; bb < 4; bb++) { vals[bb] = a[(c * 4 + bb) * NH + h]; mx = fmaxf(mx, vals[bb]); }
        float ssum = 0.f;
#pragma unroll
        for (int bb = 0; bb < 4; bb++) { vals[bb] = __expf(vals[bb] - mx); ssum += vals[bb]; }
        float inv = 1.0f / ssum;
        float s0 = vals[0] * inv, s1 = vals[1] * inv, s2 = vals[2] * inv, s3 = vals[3] * inv;
        const float* p0 = W + (size_t)(0 * NH + h) * 4096;
        const float* p1 = W + (size_t)(1 * NH + h) * 4096;
        const float* p2 = W + (size_t)(2 * NH + h) * 4096;
        const float* p3 = W + (size_t)(3 * NH + h) * 4096;
        for (int e = tid; e < 4096; e += 256) {
            float v = s0 * p0[e] + s1 * p1[e] + s2 * p2[e] + s3 * p3[e];
            int mm = e >> 6, nn = e & 63;
            outp[nn * 64 + mm] = f2bf(v);     // transposed store
        }
        return;
    }

    int xcd = bid & 7, local = bid >> 3;          // 0..119
    int t = local / 40, rem = local % 40;
    int ti = rem >> 1, half = rem & 1;
    int qtr = xcd & 3, b = xcd >> 2;

    int nTot = startPad[b * (NSEL + 1) + NSEL];
    if (ti * 64 >= nTot) return;
    int sel = rowc[b * NP + ti * 64];
    const unsigned short* XcT = Xc + ((size_t)t * BQ + b) * NN * DMD;
    const unsigned short* L = Lt + (size_t)(t * NSEL + sel) * DMD * 512;   // [n][k] bf16

    int wave = tid >> 6, lane = tid & 63;
    int m = lane & 15, q = lane >> 4;
    if (tid < 64) toks[tid] = perm[b * NP + ti * 64 + tid];
    __syncthreads();

    int xr = tid >> 2, xc0 = (tid & 3) * 16;
    int xtok = toks[xr];
    const unsigned short* xbase = (xtok >= 0) ? &XcT[(size_t)xtok * DMD] : (const unsigned short*)0;
    int lrow = tid >> 2, lc0 = (tid & 3) * 16;
    const unsigned short* lbase = &L[(size_t)(qtr * 128 + half * 64 + lrow) * 512 + lc0];

    u16x8 rx0 = {0, 0, 0, 0, 0, 0, 0, 0}, rx1 = {0, 0, 0, 0, 0, 0, 0, 0};
    u16x8 rl0, rl1;
    if (xbase) { rx0 = *(const u16x8*)&xbase[xc0]; rx1 = *(const u16x8*)&xbase[xc0 + 8]; }
    rl0 = *(const u16x8*)&lbase[0];
    rl1 = *(const u16x8*)&lbase[8];

    f32x4 acc[4];
#pragma unroll
    for (int mt = 0; mt < 4; mt++) acc[mt] = {0, 0, 0, 0};

    for (int kb = 0; kb < DMD; kb += 64) {
        *(u16x8*)&Xb[xr][xc0] = rx0;
        *(u16x8*)&Xb[xr][xc0 + 8] = rx1;
        *(u16x8*)&Lb[lrow][lc0] = rl0;
        *(u16x8*)&Lb[lrow][lc0 + 8] = rl1;
        __syncthreads();
        if (kb + 64 < DMD) {   // prefetch next slab (overlaps MFMAs)
            int nk = kb + 64;
            if (xbase) { rx0 = *(const u16x8*)&xbase[nk + xc0]; rx1 = *(const u16x8*)&xbase[nk + xc0 + 8]; }
            rl0 = *(const u16x8*)&lbase[nk];
            rl1 = *(const u16x8*)&lbase[nk + 8];
        }
#pragma unroll
        for (int kc = 0; kc < 64; kc += 32) {
            bf16x8 bfrag = *(const bf16x8*)&Lb[wave * 16 + m][kc + q * 8];
#pragma unroll
            for (int mt = 0; mt < 4; mt++) {
                bf16x8 a = *(const bf16x8*)&Xb[mt * 16 + m][kc + q * 8];
                acc[mt] = __builtin_amdgcn_mfma_f32_16x16x32_bf16(a, bfrag, acc[mt], 0, 0, 0);
            }
        }
        __syncthreads();
    }

    if (t < 2) {
        unsigned short* O = (t == 0) ? Qb : Kb;
        int hk = qtr * 128 + half * 64 + wave * 16 + m;
        int h = hk >> 6, k0 = hk & 63;
#pragma unroll
        for (int mt = 0; mt < 4; mt++)
#pragma unroll
            for (int gg = 0; gg < 4; gg++) {
                int i = mt * 16 + q * 4 + gg;
                O[(((size_t)b * NH + h) * NP + ti * 64 + i) * 64 + k0] = f2bf(acc[mt][gg]);
            }
    } else {
        // transpose via Lb (dead), write Vt[b][h][d][ip] coalesced
#pragma unroll
        for (int mt = 0; mt < 4; mt++)
#pragma unroll
            for (int gg = 0; gg < 4; gg++)
                Lb[wave * 16 + m][mt * 16 + q * 4 + gg] = f2bf(acc[mt][gg]);
        __syncthreads();
        int hkl = tid >> 2, part = tid & 3;
        int hk = qtr * 128 + half * 64 + hkl;
        int h = hk >> 6, d = hk & 63;
        unsigned short* vp = Vt + (((size_t)b * NH + h) * DKK + d) * NP + ti * 64 + part * 16;
        *(u16x8*)&vp[0] = *(const u16x8*)&Lb[hkl][part * 16];
        *(u16x8*)&vp[8] = *(const u16x8*)&Lb[hkl][part * 16 + 8];
    }
}

// ---------------------------------------------------------------- fused attention: 512 threads, XCD-swizzled
// Round-9 base + phase-1 ONLINE PER-SLOT SOFTMAX: sarr (48 persistent f32 across the phase-1/2
// barrier) replaced by smax[3][4] (12 regs) — each slot computes scores transiently, writes
// exp(s - slotmax) to S immediately, and phase 2 rescales S by exp(slotmax - gmax) while
// accumulating row sums. This frees the register budget for the FULL-slot K double-buffer
// (kB[8]+mjB) that round 8 proved beneficial-in-intent but spilled (WRITE_SIZE 4->44.8 MB).
// Tripwires: WRITE_SIZE (spill) and absmax (one extra bf16 rounding on S; expect <= ~0.05).
// slotmax clamped to -1e30: avoids exp(-inf - -inf)=NaN on lanes whose slot columns are all
// padding, and preserves the all-masked-row semantics (gmax=-1e30 -> P=1 uniform) exactly.
__global__ __launch_bounds__(512, 4) void k_attn(
    const unsigned short* __restrict__ Qb, const unsigned short* __restrict__ Kb,
    const unsigned short* __restrict__ Vt, const unsigned short* __restrict__ W1bt,
    const unsigned short* __restrict__ W2bt,
    const int* __restrict__ perm, const int* __restrict__ rowc, const int* __restrict__ startPad,
    const int* __restrict__ maskI, const int* __restrict__ maskP,
    float* __restrict__ out)
{
    int bid = blockIdx.x;
    int xcd = bid & 7, local = bid >> 3;          // 0..159
    int bh = xcd * 2 + (local >= 80 ? 1 : 0);
    int it = (local >= 80) ? (local - 80) : local;
    int b = bh >> 3, h = bh & 7;
    int nTot = startPad[b * (NSEL + 1) + NSEL];
    int i0 = it * 16;
    if (i0 >= nTot) return;
    int r = rowc[b * NP + i0];
    int tiles = nTot >> 6;

    // ---- LDS union (53224 B): S | u | wred | wsum | tilec | cstart | mrow | toki
    __shared__ __align__(16) char smem[16 * SSp * 2 + NSEL * 16 * QLS * 2 + 1024 + 4 * (NPT + 6 + 16 + 16)];
    unsigned short (*S)[SSp] = (unsigned short (*)[SSp])smem;                 // phases 1-3
    unsigned short (*qloc)[16][QLS] = (unsigned short (*)[16][QLS])smem;      // phase 0b (aliases S)
    float (*pbuf)[16][64] = (float (*)[16][64])smem;                          // phase 4 (aliases S)
    unsigned short (*u)[16][QLS] = (unsigned short (*)[16][QLS])(smem + 16 * SSp * 2);
    char* tail = smem + 16 * SSp * 2 + NSEL * 16 * QLS * 2;
    float (*wred)[16] = (float (*)[16])tail;
    float (*wsum)[16] = (float (*)[16])(tail + 512);
    int* tilec = (int*)(tail + 1024);
    int* cstart = tilec + NPT;
    int* mrow = cstart + 6;
    int* toki = mrow + 16;

    int tid = threadIdx.x;
    int wave = tid >> 6, lane = tid & 63;
    int m = lane & 15, q = lane >> 4;

    const int* permB = perm + b * NP;
    const unsigned short* QbB = Qb + (size_t)bh * NP * 64;
    const unsigned short* KbB = Kb + (size_t)bh * NP * 64;
    const unsigned short* VtB = Vt + (size_t)bh * DKK * NP;      // [d][jp]
    const int* maskPB = maskP + b * NP;

    if (tid < NPT) tilec[tid] = rowc[b * NP + tid * 64];
    else if (tid >= 32 && tid < 38) cstart[tid - 32] = startPad[b * (NSEL + 1) + (tid - 32)];
    else if (tid >= 64 && tid < 80) {
        int rr = tid - 64;
        int tok = permB[i0 + rr];
        toki[rr] = tok;
        mrow[rr] = (tok >= 0) ? maskI[b * NN + tok] : 0;
    }

    // ---- phase 0b: qloc[c][i][n] = Q . W1m[cls(r,c)]; all class W-loads batched before MFMAs
    // NOTE: qloc aliases S. Phase 1 writes S while reading qloc — DIFFERENT regions? qloc spans
    // 5*16*68*2 = 10880 B at smem+0; S row 0 starts at smem+0 too -> CONFLICT. Fix: qloc moved to
    // alias u (dead until phase 3), as in round 4's layout. (u region is 10880 B, exactly fits.)
    unsigned short (*qlocU)[16][QLS] = (unsigned short (*)[16][QLS])(smem + 16 * SSp * 2);
    {
        const unsigned short* qa = &QbB[(size_t)(i0 + m) * 64 + q * 8];
        bf16x8 a0 = *(const bf16x8*)qa;
        bf16x8 a1 = *(const bf16x8*)(qa + 32);
        int sub = wave & 3;
        int hi = wave >> 2;
        int cA = hi ? 3 : 0, cB = hi ? 4 : 1, cC = 2;       // cC only used when !hi
        size_t woff = (size_t)(sub * 16 + m) * 64 + q * 8;
        const unsigned short* wA = W1bt + (((size_t)clsOf(r, cA) * NH + h) << 12) + woff;
        const unsigned short* wB = W1bt + (((size_t)clsOf(r, cB) * NH + h) << 12) + woff;
        bf16x8 bA0 = *(const bf16x8*)wA, bA1 = *(const bf16x8*)(wA + 32);
        bf16x8 bB0 = *(const bf16x8*)wB, bB1 = *(const bf16x8*)(wB + 32);
        bf16x8 bC0 = {}, bC1 = {};
        if (!hi) {
            const unsigned short* wC = W1bt + (((size_t)clsOf(r, cC) * NH + h) << 12) + woff;
            bC0 = *(const bf16x8*)wC; bC1 = *(const bf16x8*)(wC + 32);
        }
        f32x4 acc = {0.f, 0.f, 0.f, 0.f};
        acc = __builtin_amdgcn_mfma_f32_16x16x32_bf16(a0, bA0, acc, 0, 0, 0);
        acc = __builtin_amdgcn_mfma_f32_16x16x32_bf16(a1, bA1, acc, 0, 0, 0);
#pragma unroll
        for (int g = 0; g < 4; g++) qlocU[cA][q * 4 + g][sub * 16 + m] = f2bf(acc[g]);
        acc = {0.f, 0.f, 0.f, 0.f};
        acc = __builtin_amdgcn_mfma_f32_16x16x32_bf16(a0, bB0, acc, 0, 0, 0);
        acc = __builtin_amdgcn_mfma_f32_16x16x32_bf16(a1, bB1, acc, 0, 0, 0);
#pragma unroll
        for (int g = 0; g < 4; g++) qlocU[cB][q * 4 + g][sub * 16 + m] = f2bf(acc[g]);
        if (!hi) {
            acc = {0.f, 0.f, 0.f, 0.f};
            acc = __builtin_amdgcn_mfma_f32_16x16x32_bf16(a0, bC0, acc, 0, 0, 0);
            acc = __builtin_amdgcn_mfma_f32_16x16x32_bf16(a1, bC1, acc, 0, 0, 0);
#pragma unroll
            for (int g = 0; g < 4; g++) qlocU[cC][q * 4 + g][sub * 16 + m] = f2bf(acc[g]);
        }
    }
    __syncthreads();

    // ---- phase 1: online per-slot softmax; FULL-slot K double-buffer; invalid slots skipped
    float smax[MAXT][4];
    float lmax[4] = {-INFINITY, -INFINITY, -INFINITY, -INFINITY};
    int mrow4[4];
#pragma unroll
    for (int g = 0; g < 4; g++) mrow4[g] = mrow[q * 4 + g];

    int nslots = 0;                                   // valid slots for this wave (wave-uniform)
    while (nslots < MAXT && wave + nslots * 8 < tiles) nslots++;

    bf16x8 kA[8], kB[8];
    int mjA[4], mjB[4];
    {                                                  // preload slot 0 fully (nslots >= 2 always)
        int jb = wave * 64;
#pragma unroll
        for (int nb = 0; nb < 4; nb++) {
            int j = jb + nb * 16 + m;
            const unsigned short* kb = &KbB[(size_t)j * 64 + q * 8];
            kA[nb * 2]     = *(const bf16x8*)kb;
            kA[nb * 2 + 1] = *(const bf16x8*)(kb + 32);
            mjA[nb] = maskPB[j];
        }
    }
#pragma unroll
    for (int tt = 0; tt < MAXT; tt++) {
        if (tt < nslots) {
            int jt = wave + tt * 8;
            int c = tilec[jt];
            const unsigned short* qa = &qlocU[c][m][q * 8];
            bf16x8 a0 = *(const bf16x8*)qa;
            bf16x8 a1 = *(const bf16x8*)(qa + 32);
            bool pf = (tt + 1 < nslots);
            if (pf) {                                  // issue ALL of next slot's loads before MFMAs
                int jbN = (wave + (tt + 1) * 8) * 64;
#pragma unroll
                for (int nb = 0; nb < 4; nb++) {
                    int j = jbN + nb * 16 + m;
                    const unsigned short* kb = &KbB[(size_t)j * 64 + q * 8];
                    kB[nb * 2]     = *(const bf16x8*)kb;
                    kB[nb * 2 + 1] = *(const bf16x8*)(kb + 32);
                    mjB[nb] = maskPB[j];
                }
            }
            float sv[4][4];                            // slot-transient scores
            __builtin_amdgcn_s_setprio(1);
#pragma unroll
            for (int nb = 0; nb < 4; nb++) {
                f32x4 acc = {0.f, 0.f, 0.f, 0.f};
                acc = __builtin_amdgcn_mfma_f32_16x16x32_bf16(a0, kA[nb * 2], acc, 0, 0, 0);
                acc = __builtin_amdgcn_mfma_f32_16x16x32_bf16(a1, kA[nb * 2 + 1], acc, 0, 0, 0);
                int mj = mjA[nb];
#pragma unroll
                for (int g = 0; g < 4; g++) {
                    float s;
                    if (mj == 2)             s = -INFINITY;       // padding slot
                    else if (mrow4[g] && mj) s = acc[g] * 0.125f;
                    else                     s = -1e30f;          // reference's masked value
                    sv[nb][g] = s;
                }
            }
            __builtin_amdgcn_s_setprio(0);
            int jb = jt * 64;
#pragma unroll
            for (int g = 0; g < 4; g++) {
                float mx = fmaxf(fmaxf(sv[0][g], sv[1][g]), fmaxf(sv[2][g], sv[3][g]));
                mx = fmaxf(mx, -1e30f);                // clamp: all-padding lane -> finite
                smax[tt][g] = mx;
                lmax[g] = fmaxf(lmax[g], mx);
            }
#pragma unroll
            for (int nb = 0; nb < 4; nb++) {
                int j = jb + nb * 16 + m;
#pragma unroll
                for (int g = 0; g < 4; g++) {
                    float p = __expf(sv[nb][g] - smax[tt][g]);    // -inf -> 0
                    S[q * 4 + g][j] = f2bf(p);
                }
            }
            if (pf) {                                  // rotate full buffer
#pragma unroll
                for (int i = 0; i < 8; i++) kA[i] = kB[i];
#pragma unroll
                for (int nb = 0; nb < 4; nb++) mjA[nb] = mjB[nb];
            }
        }
    }
#pragma unroll
    for (int g = 0; g < 4; g++) {
        float v = lmax[g];
#pragma unroll
        for (int o = 1; o < 16; o <<= 1) v = fmaxf(v, __shfl_xor(v, o));
        lmax[g] = v;
    }
    if (m == 0) {
#pragma unroll
        for (int g = 0; g < 4; g++) wred[wave][q * 4 + g] = lmax[g];
    }
    __syncthreads();

    // ---- phase 2: rescale S by exp(smax - gmax), accumulate row sums
    float mx4[4], lsum[4] = {0.f, 0.f, 0.f, 0.f};
#pragma unroll
    for (int g = 0; g < 4; g++) {
        int i = q * 4 + g;
        float v = wred[0][i];
#pragma unroll
        for (int w2 = 1; w2 < 8; w2++) v = fmaxf(v, wred[w2][i]);
        mx4[g] = v;
    }
#pragma unroll
    for (int tt = 0; tt < MAXT; tt++) {
        if (tt < nslots) {                             // wave-uniform skip
            int jb = (wave + tt * 8) * 64;
            float f4[4];
#pragma unroll
            for (int g = 0; g < 4; g++) f4[g] = __expf(smax[tt][g] - mx4[g]);   // <= 1
#pragma unroll
            for (int nb = 0; nb < 4; nb++) {
                int j = jb + nb * 16 + m;
#pragma unroll
                for (int g = 0; g < 4; g++) {
                    float pv = bf2f(S[q * 4 + g][j]) * f4[g];
                    lsum[g] += pv;
                    S[q * 4 + g][j] = f2bf(pv);
                }
            }
        }
    }
#pragma unroll
    for (int g = 0; g < 4; g++) {
        float v = lsum[g];
#pragma unroll
        for (int o = 1; o < 16; o <<= 1) v += __shfl_xor(v, o);
        lsum[g] = v;
    }
    if (m == 0) {
#pragma unroll
        for (int g = 0; g < 4; g++) wsum[wave][q * 4 + g] = lsum[g];
    }
    __syncthreads();

    // ---- phase 3: per-class PV into u; wave = (kw, c-half)
    //      dynamic split point sc balances tile counts between wave halves;
    //      1-deep register prefetch of S-row + V-row carried across class boundaries.
    {
        int kw = wave & 3, chalf = wave >> 2;
        int db = kw * 16;
        int nT2 = cstart[5];
        int sc = 1, best = 0x7fffffff;
#pragma unroll
        for (int c = 1; c <= 4; c++) {
            int d = 2 * cstart[c] - nT2;
            d = d < 0 ? -d : d;
            if (d < best) { best = d; sc = c; }
        }
        int cb = chalf ? sc : 0, ce = chalf ? 5 : sc;
        int t0 = cstart[cb] >> 6, tEnd = cstart[ce] >> 6;
        const unsigned short* Srow = &S[m][q * 8];
        const unsigned short* Vrow = &VtB[(size_t)(db + m) * NP + q * 8];
        bf16x8 a0 = {}, a1 = {}, b0 = {}, b1 = {};
        if (t0 < tEnd) {
            int jb = t0 * 64;
            a0 = *(const bf16x8*)&Srow[jb];  a1 = *(const bf16x8*)&Srow[jb + 32];
            b0 = *(const bf16x8*)&Vrow[jb];  b1 = *(const bf16x8*)&Vrow[jb + 32];
        }
        int tcur = t0;
        for (int c = cb; c < ce; c++) {
            int ct1 = cstart[c + 1] >> 6;
            f32x4 ae = {0.f, 0.f, 0.f, 0.f};
            f32x4 ao = {0.f, 0.f, 0.f, 0.f};
            while (tcur < ct1) {
                bf16x8 ca0 = a0, ca1 = a1, cb0 = b0, cb1 = b1;
                int tn = tcur + 1;
                if (tn < tEnd) {             // prefetch next tile (crosses class boundary)
                    int jb = tn * 64;
                    a0 = *(const bf16x8*)&Srow[jb];  a1 = *(const bf16x8*)&Srow[jb + 32];
                    b0 = *(const bf16x8*)&Vrow[jb];  b1 = *(const bf16x8*)&Vrow[jb + 32];
                }
                __builtin_amdgcn_s_setprio(1);
                ae = __builtin_amdgcn_mfma_f32_16x16x32_bf16(ca0, cb0, ae, 0, 0, 0);
                ao = __builtin_amdgcn_mfma_f32_16x16x32_bf16(ca1, cb1, ao, 0, 0, 0);
                __builtin_amdgcn_s_setprio(0);
                tcur++;
            }
#pragma unroll
            for (int g = 0; g < 4; g++)
                u[c][q * 4 + g][db + m] = f2bf(ae[g] + ao[g]);
        }
    }
    __syncthreads();   // S dead from here; pbuf region reusable

    // ---- phase 4: out = (sum_c u[c] . W2m[cls(r,c)]); class W-loads batched before MFMAs
    {
        int kw = wave & 3, p = wave >> 2;
        int cA = p ? 3 : 0, cB = p ? 4 : 1, cC = 2;         // cC only used when !p
        size_t woff = (size_t)(kw * 16 + m) * 64 + q * 8;
        const unsigned short* wA = W2bt + (((size_t)clsOf(r, cA) * NH + h) << 12) + woff;
        const unsigned short* wB = W2bt + (((size_t)clsOf(r, cB) * NH + h) << 12) + woff;
        bf16x8 bA0 = *(const bf16x8*)wA, bA1 = *(const bf16x8*)(wA + 32);
        bf16x8 bB0 = *(const bf16x8*)wB, bB1 = *(const bf16x8*)(wB + 32);
        bf16x8 bC0 = {}, bC1 = {};
        if (!p) {
            const unsigned short* wC = W2bt + (((size_t)clsOf(r, cC) * NH + h) << 12) + woff;
            bC0 = *(const bf16x8*)wC; bC1 = *(const bf16x8*)(wC + 32);
        }
        f32x4 acc = {0.f, 0.f, 0.f, 0.f};
        {
            const unsigned short* ua = &u[cA][m][q * 8];
            bf16x8 a0 = *(const bf16x8*)ua;
            bf16x8 a1 = *(const bf16x8*)(ua + 32);
            acc = __builtin_amdgcn_mfma_f32_16x16x32_bf16(a0, bA0, acc, 0, 0, 0);
            acc = __builtin_amdgcn_mfma_f32_16x16x32_bf16(a1, bA1, acc, 0, 0, 0);
        }
        {
            const unsigned short* ua = &u[cB][m][q * 8];
            bf16x8 a0 = *(const bf16x8*)ua;
            bf16x8 a1 = *(const bf16x8*)(ua + 32);
            acc = __builtin_amdgcn_mfma_f32_16x16x32_bf16(a0, bB0, acc, 0, 0, 0);
            acc = __builtin_amdgcn_mfma_f32_16x16x32_bf16(a1, bB1, acc, 0, 0, 0);
        }
        if (!p) {
            const unsigned short* ua = &u[cC][m][q * 8];
            bf16x8 a0 = *(const bf16x8*)ua;
            bf16x8 a1 = *(const bf16x8*)(ua + 32);
            acc = __builtin_amdgcn_mfma_f32_16x16x32_bf16(a0, bC0, acc, 0, 0, 0);
            acc = __builtin_amdgcn_mfma_f32_16x16x32_bf16(a1, bC1, acc, 0, 0, 0);
        }
#pragma unroll
        for (int g = 0; g < 4; g++)
            pbuf[p][q * 4 + g][kw * 16 + m] = acc[g];
    }
    __syncthreads();

    // ---- epilogue: combine halves, normalize, store
    for (int idx = tid; idx < 16 * 64; idx += 512) {
        int i = idx >> 6, k = idx & 63;
        int tok = toki[i];
        if (tok >= 0) {
            float s = wsum[0][i] + wsum[1][i] + wsum[2][i] + wsum[3][i]
                    + wsum[4][i] + wsum[5][i] + wsum[6][i] + wsum[7][i];
            float v = pbuf[0][i][k] + pbuf[1][i][k];
            out[((size_t)b * NN + tok) * (NH * DKK) + h * DKK + k] = v / s;
        }
    }
}

// ---------------------------------------------------------------- launch
extern "C" void kernel_launch(void* const* d_in, const int* in_sizes, int n_in,
                              void* d_out, int out_size, void* d_ws, size_t ws_size,
                              hipStream_t stream)
{
    const float* qr  = (const float*)d_in[0];
    const float* kr  = (const float*)d_in[1];
    const float* vr  = (const float*)d_in[2];
    const void* bsr  = d_in[3];
    const void* mkr  = d_in[4];
    const float* lr  = (const float*)d_in[5];
    const float* w1r = (const float*)d_in[6];
    const float* a1r = (const float*)d_in[7];
    const float* w2r = (const float*)d_in[8];
    const float* a2r = (const float*)d_in[9];
    float* out = (float*)d_out;

    char* w = (char*)d_ws;
    int* maskI    = (int*)w;
    int* perm     = maskI + BQ * NN;
    int* rowc     = perm + BQ * NP;
    int* startPad = rowc + BQ * NP;
    int* maskP    = startPad + 12;
    unsigned short* W1bt = (unsigned short*)(w + 65536);
    unsigned short* W2bt = W1bt + (size_t)NCLS * NH * 4096;
    unsigned short* Qb   = (unsigned short*)(w + 2359296);
    unsigned short* Kb   = Qb + (size_t)BQ * NH * NP * 64;
    unsigned short* Vt   = Kb + (size_t)BQ * NH * NP * 64;           // [b][h][d][ip]
    unsigned short* Lt   = (unsigned short*)(w + 10616832);
    unsigned short* Xc   = (unsigned short*)(w + 26345472);          // total ~32.6 MB

    hipLaunchKernelGGL(k_prep, dim3(960 + 96 + 1), dim3(256), 0, stream,
                       lr, Lt, qr, kr, vr, Xc,
                       bsr, mkr, maskI, perm, rowc, startPad, maskP);
    hipLaunchKernelGGL(k_proj, dim3(960 + 2 * NCLS * NH), dim3(256), 0, stream,
                       Xc, Lt, perm, rowc, startPad, Qb, Kb, Vt,
                       w1r, w2r, a1r, a2r, W1bt, W2bt);
    hipLaunchKernelGGL(k_attn, dim3(8 * 2 * 80), dim3(512), 0, stream,
                       Qb, Kb, Vt, W1bt, W2bt, perm, rowc, startPad, maskI, maskP, out);
}

// Round 11
// 180.338 us; speedup vs baseline: 1.0553x; 1.0553x over previous
//
#include <hip/hip_runtime.h>
#include <hip/hip_bf16.h>
#include <math.h>

#define BQ   2      // batch
#define NN   1024   // seq len
#define DMD  512    // d_model
#define NH   8      // heads
#define DKK  64     // head dim
#define NSEL 5      // NB+1 block values (0..4)
#define NCLS 17     // block-pair classes
#define NP   1280   // padded per-batch capacity: nTot = sum(ceil(c_i/64)*64) <= 1339 and %64==0 -> <=1280
#define NPT  20     // NP/64 tiles
#define MAXT 3      // max key-tiles per wave in k_attn (ceil(20/8))
#define SSp  1284   // S row stride (shorts): 2568B = 642 words == 2 mod 32 banks, conflict-free shift
#define QLS  68     // qloc/u row stride (shorts)

typedef __attribute__((ext_vector_type(8))) short bf16x8;
typedef __attribute__((ext_vector_type(8))) unsigned short u16x8;
typedef __attribute__((ext_vector_type(4))) float f32x4;

__device__ __forceinline__ int clsOf(int r, int c) { return (r == 0 || c == 0) ? 0 : ((r - 1) * 4 + c); }

__device__ __forceinline__ unsigned short f2bf(float x) {
    __hip_bfloat16 h = __float2bfloat16(x);
    return *reinterpret_cast<unsigned short*>(&h);
}

// ---------------------------------------------------------------- prep: lin cast (960) + qkv cast (96) + setup (1)
__global__ __launch_bounds__(256) void k_prep(
    const float* __restrict__ lr, unsigned short* __restrict__ Lt,
    const float* __restrict__ qr, const float* __restrict__ kr, const float* __restrict__ vr,
    unsigned short* __restrict__ Xc,
    const void* __restrict__ b_seq_r, const void* __restrict__ mask_r,
    int* __restrict__ maskI, int* __restrict__ perm, int* __restrict__ rowc,
    int* __restrict__ startPad, int* __restrict__ maskP)
{
    __shared__ float Tf[64][68];
    __shared__ int det[5];
    __shared__ int cnts[BQ][NSEL];
    __shared__ int offs[BQ][NSEL];
    __shared__ int sstart[BQ][NSEL + 1];
    int bx = blockIdx.x;
    int tid = threadIdx.x;
    if (bx < 960) {
        // cast+transpose lin[ts][k][n] -> Lt[ts][n][k] bf16
        int ts = bx >> 6, rem = bx & 63;
        int kt = rem >> 3, nt = rem & 7;
        const float* src = lr + (size_t)ts * DMD * 512;
        unsigned short* dst = Lt + (size_t)ts * DMD * 512;
        int r = tid >> 2, c4 = tid & 3;
#pragma unroll
        for (int i = 0; i < 4; i++) {
            float4 v = *(const float4*)&src[(size_t)(kt * 64 + r) * 512 + nt * 64 + c4 * 16 + i * 4];
            *(float4*)&Tf[r][c4 * 16 + i * 4] = v;
        }
        __syncthreads();
        unsigned short tmp[16];
#pragma unroll
        for (int i = 0; i < 16; i++) tmp[i] = f2bf(Tf[c4 * 16 + i][r]);
        u16x8 o0, o1;
#pragma unroll
        for (int i = 0; i < 8; i++) { o0[i] = tmp[i]; o1[i] = tmp[8 + i]; }
        unsigned short* dp = &dst[(size_t)(nt * 64 + r) * 512 + kt * 64 + c4 * 16];
        *(u16x8*)&dp[0] = o0;
        *(u16x8*)&dp[8] = o1;
    } else if (bx < 960 + 96) {
        // cast q/k/v -> Xc bf16 [t][b][n][512]
        int bid = bx - 960;                     // 0..95
        int t = bid / 32, rem = bid % 32;
        int b = rem / 16, rg = rem % 16;
        int row = tid >> 2, part = tid & 3;
        const float* X = (t == 0) ? qr : ((t == 1) ? kr : vr);
        const float* src = X + ((size_t)b * NN + rg * 64 + row) * DMD + part * 128;
        unsigned short* dst = Xc + (((size_t)t * BQ + b) * NN + rg * 64 + row) * DMD + part * 128;
#pragma unroll
        for (int i = 0; i < 128; i += 8) {
            float4 v0 = *(const float4*)&src[i];
            float4 v1 = *(const float4*)&src[i + 4];
            u16x8 o;
            o[0] = f2bf(v0.x); o[1] = f2bf(v0.y); o[2] = f2bf(v0.z); o[3] = f2bf(v0.w);
            o[4] = f2bf(v1.x); o[5] = f2bf(v1.y); o[6] = f2bf(v1.z); o[7] = f2bf(v1.w);
            *(u16x8*)&dst[i] = o;
        }
    } else {
        // ---- setup (single block): dtype detect, bucketize, perm, masks
        if (tid < 5) det[tid] = 0;
        if (tid < BQ * NSEL) { cnts[tid / NSEL][tid % NSEL] = 0; offs[tid / NSEL][tid % NSEL] = 0; }
        __syncthreads();
        const int* b32 = (const int*)b_seq_r;
        const unsigned char* mb = (const unsigned char*)mask_r;
        const int* m32 = (const int*)mask_r;
        if (tid < 64) {
            if (b32[2 * tid + 1] != 0) atomicOr(&det[0], 1);
            if (b32[2 * tid] != 0)     atomicOr(&det[1], 1);
            if (m32[2 * tid + 1] != 0) atomicOr(&det[3], 1);
            if (m32[2 * tid] != 0)     atomicOr(&det[4], 1);
        }
        if ((tid & 3) != 0 && mb[tid] != 0) atomicOr(&det[2], 1);
        __syncthreads();
        int bsI64 = (det[0] == 0 && det[1] != 0);
        int mk = det[2] ? 1 : ((det[3] == 0 && det[4] != 0) ? 2 : 0);

        for (int g = tid; g < BQ * NN; g += 256) {
            int m = (mk == 1) ? (mb[g] != 0) : ((mk == 2) ? (m32[2 * g] != 0) : (m32[g] != 0));
            maskI[g] = m;
            int bs = bsI64 ? b32[2 * g] : b32[g];
            bs = bs < 0 ? 0 : (bs > 4 ? 4 : bs);
            atomicAdd(&cnts[g / NN][bs], 1);
        }
        __syncthreads();
        if (tid == 0) {
            for (int b = 0; b < BQ; b++) {
                int acc = 0;
                for (int c = 0; c < NSEL; c++) {
                    sstart[b][c] = acc;
                    acc += ((cnts[b][c] + 63) / 64) * 64;
                }
                sstart[b][NSEL] = acc;
                for (int c = 0; c <= NSEL; c++) startPad[b * (NSEL + 1) + c] = sstart[b][c];
            }
        }
        __syncthreads();
        for (int g = tid; g < BQ * NP; g += 256) {
            perm[g] = -1;
            int b = g / NP, sslot = g % NP;
            int c = 0;
            for (int cc = 1; cc < NSEL; cc++) if (sslot >= sstart[b][cc]) c = cc;
            rowc[g] = c;
        }
        __syncthreads();
        for (int g = tid; g < BQ * NN; g += 256) {
            int b = g / NN, n = g % NN;
            int bs = bsI64 ? b32[2 * g] : b32[g];
            bs = bs < 0 ? 0 : (bs > 4 ? 4 : bs);
            int pos = sstart[b][bs] + atomicAdd(&offs[b][bs], 1);
            perm[b * NP + pos] = n;
        }
        __syncthreads();
        for (int g = tid; g < BQ * NP; g += 256) {
            int tok = perm[g];
            maskP[g] = (tok < 0) ? 2 : maskI[(g / NP) * NN + tok];
        }
    }
}

// ---------------------------------------------------------------- QKV projection (960 blocks) + wmix (272 blocks)
__global__ __launch_bounds__(256) void k_proj(
    const unsigned short* __restrict__ Xc,
    const unsigned short* __restrict__ Lt,
    const int* __restrict__ perm, const int* __restrict__ rowc, const int* __restrict__ startPad,
    unsigned short* __restrict__ Qb, unsigned short* __restrict__ Kb,
    unsigned short* __restrict__ Vt,
    const float* __restrict__ W1, const float* __restrict__ W2,
    const float* __restrict__ al1, const float* __restrict__ al2,
    unsigned short* __restrict__ W1bt, unsigned short* __restrict__ W2bt)
{
    __shared__ __align__(16) unsigned short Xb[64][72];
    __shared__ __align__(16) unsigned short Lb[64][72];
    __shared__ int toks[64];

    int bid = blockIdx.x;
    int tid = threadIdx.x;
    if (bid >= 960) {
        // ---- wmix: W1m/W2m mixtures, transposed bf16
        int bid2 = bid - 960;
        int w = bid2 / (NCLS * NH);
        int rem = bid2 % (NCLS * NH);
        int c = rem / NH, h = rem % NH;
        const float* W = w ? W2 : W1;
        const float* a = w ? al2 : al1;
        unsigned short* outp = (w ? W2bt : W1bt) + (((size_t)c * NH + h) << 12);
        float vals[4], mx = -1e30f;
#pragma unroll
        for (int bb = 0; bb < 4; bb++) { vals[bb] = a[(c * 4 + bb) * NH + h]; mx = fmaxf(mx, vals[bb]); }
        float ssum = 0.f;
#pragma unroll
        for (int bb = 0; bb < 4; bb++) { vals[bb] = __expf(vals[bb] - mx); ssum += vals[bb]; }
        float inv = 1.0f / ssum;
        float s0 = vals[0] * inv, s1 = vals[1] * inv, s2 = vals[2] * inv, s3 = vals[3] * inv;
        const float* p0 = W + (size_t)(0 * NH + h) * 4096;
        const float* p1 = W + (size_t)(1 * NH + h) * 4096;
        const float* p2 = W + (size_t)(2 * NH + h) * 4096;
        const float* p3 = W + (size_t)(3 * NH + h) * 4096;
        for (int e = tid; e < 4096; e += 256) {
            float v = s0 * p0[e] + s1 * p1[e] + s2 * p2[e] + s3 * p3[e];
            int mm = e >> 6, nn = e & 63;
            outp[nn * 64 + mm] = f2bf(v);     // transposed store
        }
        return;
    }

    int xcd = bid & 7, local = bid >> 3;          // 0..119
    int t = local / 40, rem = local % 40;
    int ti = rem >> 1, half = rem & 1;
    int qtr = xcd & 3, b = xcd >> 2;

    int nTot = startPad[b * (NSEL + 1) + NSEL];
    if (ti * 64 >= nTot) return;
    int sel = rowc[b * NP + ti * 64];
    const unsigned short* XcT = Xc + ((size_t)t * BQ + b) * NN * DMD;
    const unsigned short* L = Lt + (size_t)(t * NSEL + sel) * DMD * 512;   // [n][k] bf16

    int wave = tid >> 6, lane = tid & 63;
    int m = lane & 15, q = lane >> 4;
    if (tid < 64) toks[tid] = perm[b * NP + ti * 64 + tid];
    __syncthreads();

    int xr = tid >> 2, xc0 = (tid & 3) * 16;
    int xtok = toks[xr];
    const unsigned short* xbase = (xtok >= 0) ? &XcT[(size_t)xtok * DMD] : (const unsigned short*)0;
    int lrow = tid >> 2, lc0 = (tid & 3) * 16;
    const unsigned short* lbase = &L[(size_t)(qtr * 128 + half * 64 + lrow) * 512 + lc0];

    u16x8 rx0 = {0, 0, 0, 0, 0, 0, 0, 0}, rx1 = {0, 0, 0, 0, 0, 0, 0, 0};
    u16x8 rl0, rl1;
    if (xbase) { rx0 = *(const u16x8*)&xbase[xc0]; rx1 = *(const u16x8*)&xbase[xc0 + 8]; }
    rl0 = *(const u16x8*)&lbase[0];
    rl1 = *(const u16x8*)&lbase[8];

    f32x4 acc[4];
#pragma unroll
    for (int mt = 0; mt < 4; mt++) acc[mt] = {0, 0, 0, 0};

    for (int kb = 0; kb < DMD; kb += 64) {
        *(u16x8*)&Xb[xr][xc0] = rx0;
        *(u16x8*)&Xb[xr][xc0 + 8] = rx1;
        *(u16x8*)&Lb[lrow][lc0] = rl0;
        *(u16x8*)&Lb[lrow][lc0 + 8] = rl1;
        __syncthreads();
        if (kb + 64 < DMD) {   // prefetch next slab (overlaps MFMAs)
            int nk = kb + 64;
            if (xbase) { rx0 = *(const u16x8*)&xbase[nk + xc0]; rx1 = *(const u16x8*)&xbase[nk + xc0 + 8]; }
            rl0 = *(const u16x8*)&lbase[nk];
            rl1 = *(const u16x8*)&lbase[nk + 8];
        }
#pragma unroll
        for (int kc = 0; kc < 64; kc += 32) {
            bf16x8 bfrag = *(const bf16x8*)&Lb[wave * 16 + m][kc + q * 8];
#pragma unroll
            for (int mt = 0; mt < 4; mt++) {
                bf16x8 a = *(const bf16x8*)&Xb[mt * 16 + m][kc + q * 8];
                acc[mt] = __builtin_amdgcn_mfma_f32_16x16x32_bf16(a, bfrag, acc[mt], 0, 0, 0);
            }
        }
        __syncthreads();
    }

    if (t < 2) {
        unsigned short* O = (t == 0) ? Qb : Kb;
        int hk = qtr * 128 + half * 64 + wave * 16 + m;
        int h = hk >> 6, k0 = hk & 63;
#pragma unroll
        for (int mt = 0; mt < 4; mt++)
#pragma unroll
            for (int gg = 0; gg < 4; gg++) {
                int i = mt * 16 + q * 4 + gg;
                O[(((size_t)b * NH + h) * NP + ti * 64 + i) * 64 + k0] = f2bf(acc[mt][gg]);
            }
    } else {
        // transpose via Lb (dead), write Vt[b][h][d][ip] coalesced
#pragma unroll
        for (int mt = 0; mt < 4; mt++)
#pragma unroll
            for (int gg = 0; gg < 4; gg++)
                Lb[wave * 16 + m][mt * 16 + q * 4 + gg] = f2bf(acc[mt][gg]);
        __syncthreads();
        int hkl = tid >> 2, part = tid & 3;
        int hk = qtr * 128 + half * 64 + hkl;
        int h = hk >> 6, d = hk & 63;
        unsigned short* vp = Vt + (((size_t)b * NH + h) * DKK + d) * NP + ti * 64 + part * 16;
        *(u16x8*)&vp[0] = *(const u16x8*)&Lb[hkl][part * 16];
        *(u16x8*)&vp[8] = *(const u16x8*)&Lb[hkl][part * 16 + 8];
    }
}

// ---------------------------------------------------------------- fused attention: 512 threads, XCD-swizzled
// Round-9 base (71.9 us: half-slot K prefetch + sarr + skip + setprio + batched W-loads; round-10's
// online-softmax refactor regressed to 75.8 with a small spill and was reverted). New, isolated:
// phase-3 V prefetch deepened 1->2 (S stays 1-deep, LDS-cheap). Phase 3's per-tile compute is
// only 2 MFMAs vs ~200cyc V L2 latency, so 1-deep covered almost nothing; and phase 3 is NOT the
// kernel's register-pressure peak (sarr dead), so +16 regs here can't trigger the rounds-8/10
// spill (kernel VGPR peak stays in phase 1). Tripwire: WRITE_SIZE must stay 4096 KB.
__global__ __launch_bounds__(512, 4) void k_attn(
    const unsigned short* __restrict__ Qb, const unsigned short* __restrict__ Kb,
    const unsigned short* __restrict__ Vt, const unsigned short* __restrict__ W1bt,
    const unsigned short* __restrict__ W2bt,
    const int* __restrict__ perm, const int* __restrict__ rowc, const int* __restrict__ startPad,
    const int* __restrict__ maskI, const int* __restrict__ maskP,
    float* __restrict__ out)
{
    int bid = blockIdx.x;
    int xcd = bid & 7, local = bid >> 3;          // 0..159
    int bh = xcd * 2 + (local >= 80 ? 1 : 0);
    int it = (local >= 80) ? (local - 80) : local;
    int b = bh >> 3, h = bh & 7;
    int nTot = startPad[b * (NSEL + 1) + NSEL];
    int i0 = it * 16;
    if (i0 >= nTot) return;
    int r = rowc[b * NP + i0];
    int tiles = nTot >> 6;

    // ---- LDS union (53224 B): S | u(|qloc) | wred | wsum | tilec | cstart | mrow | toki
    __shared__ __align__(16) char smem[16 * SSp * 2 + NSEL * 16 * QLS * 2 + 1024 + 4 * (NPT + 6 + 16 + 16)];
    unsigned short (*S)[SSp] = (unsigned short (*)[SSp])smem;                 // phases 2-3
    float (*pbuf)[16][64] = (float (*)[16][64])smem;                          // phase 4 (aliases S)
    unsigned short (*u)[16][QLS] = (unsigned short (*)[16][QLS])(smem + 16 * SSp * 2);
    unsigned short (*qloc)[16][QLS] = (unsigned short (*)[16][QLS])(smem + 16 * SSp * 2); // phases 0b-1 (aliases u)
    char* tail = smem + 16 * SSp * 2 + NSEL * 16 * QLS * 2;
    float (*wred)[16] = (float (*)[16])tail;
    float (*wsum)[16] = (float (*)[16])(tail + 512);
    int* tilec = (int*)(tail + 1024);
    int* cstart = tilec + NPT;
    int* mrow = cstart + 6;
    int* toki = mrow + 16;

    int tid = threadIdx.x;
    int wave = tid >> 6, lane = tid & 63;
    int m = lane & 15, q = lane >> 4;

    const int* permB = perm + b * NP;
    const unsigned short* QbB = Qb + (size_t)bh * NP * 64;
    const unsigned short* KbB = Kb + (size_t)bh * NP * 64;
    const unsigned short* VtB = Vt + (size_t)bh * DKK * NP;      // [d][jp]
    const int* maskPB = maskP + b * NP;

    if (tid < NPT) tilec[tid] = rowc[b * NP + tid * 64];
    else if (tid >= 32 && tid < 38) cstart[tid - 32] = startPad[b * (NSEL + 1) + (tid - 32)];
    else if (tid >= 64 && tid < 80) {
        int rr = tid - 64;
        int tok = permB[i0 + rr];
        toki[rr] = tok;
        mrow[rr] = (tok >= 0) ? maskI[b * NN + tok] : 0;
    }

    // ---- phase 0b: qloc[c][i][n] = Q . W1m[cls(r,c)]; all class W-loads batched before MFMAs
    {
        const unsigned short* qa = &QbB[(size_t)(i0 + m) * 64 + q * 8];
        bf16x8 a0 = *(const bf16x8*)qa;
        bf16x8 a1 = *(const bf16x8*)(qa + 32);
        int sub = wave & 3;
        int hi = wave >> 2;
        int cA = hi ? 3 : 0, cB = hi ? 4 : 1, cC = 2;       // cC only used when !hi
        size_t woff = (size_t)(sub * 16 + m) * 64 + q * 8;
        const unsigned short* wA = W1bt + (((size_t)clsOf(r, cA) * NH + h) << 12) + woff;
        const unsigned short* wB = W1bt + (((size_t)clsOf(r, cB) * NH + h) << 12) + woff;
        bf16x8 bA0 = *(const bf16x8*)wA, bA1 = *(const bf16x8*)(wA + 32);
        bf16x8 bB0 = *(const bf16x8*)wB, bB1 = *(const bf16x8*)(wB + 32);
        bf16x8 bC0 = {}, bC1 = {};
        if (!hi) {
            const unsigned short* wC = W1bt + (((size_t)clsOf(r, cC) * NH + h) << 12) + woff;
            bC0 = *(const bf16x8*)wC; bC1 = *(const bf16x8*)(wC + 32);
        }
        f32x4 acc = {0.f, 0.f, 0.f, 0.f};
        acc = __builtin_amdgcn_mfma_f32_16x16x32_bf16(a0, bA0, acc, 0, 0, 0);
        acc = __builtin_amdgcn_mfma_f32_16x16x32_bf16(a1, bA1, acc, 0, 0, 0);
#pragma unroll
        for (int g = 0; g < 4; g++) qloc[cA][q * 4 + g][sub * 16 + m] = f2bf(acc[g]);
        acc = {0.f, 0.f, 0.f, 0.f};
        acc = __builtin_amdgcn_mfma_f32_16x16x32_bf16(a0, bB0, acc, 0, 0, 0);
        acc = __builtin_amdgcn_mfma_f32_16x16x32_bf16(a1, bB1, acc, 0, 0, 0);
#pragma unroll
        for (int g = 0; g < 4; g++) qloc[cB][q * 4 + g][sub * 16 + m] = f2bf(acc[g]);
        if (!hi) {
            acc = {0.f, 0.f, 0.f, 0.f};
            acc = __builtin_amdgcn_mfma_f32_16x16x32_bf16(a0, bC0, acc, 0, 0, 0);
            acc = __builtin_amdgcn_mfma_f32_16x16x32_bf16(a1, bC1, acc, 0, 0, 0);
#pragma unroll
            for (int g = 0; g < 4; g++) qloc[cC][q * 4 + g][sub * 16 + m] = f2bf(acc[g]);
        }
    }
    __syncthreads();

    // ---- phase 1 (round-9 verbatim): half-slot prefetch, invalid slots skipped, setprio
    float sarr[MAXT][4][4];
    float lmax[4] = {-INFINITY, -INFINITY, -INFINITY, -INFINITY};
    int mrow4[4];
#pragma unroll
    for (int g = 0; g < 4; g++) mrow4[g] = mrow[q * 4 + g];

    int nslots = 0;                                   // valid slots for this wave (wave-uniform)
    while (nslots < MAXT && wave + nslots * 8 < tiles) nslots++;

    bf16x8 kA[8], kB[4];
    int mjA[4];
    if (nslots > 0) {                                  // preload slot 0 fully
        int jb = wave * 64;
#pragma unroll
        for (int nb = 0; nb < 4; nb++) {
            int j = jb + nb * 16 + m;
            const unsigned short* kb = &KbB[(size_t)j * 64 + q * 8];
            kA[nb * 2]     = *(const bf16x8*)kb;
            kA[nb * 2 + 1] = *(const bf16x8*)(kb + 32);
            mjA[nb] = maskPB[j];
        }
    }
#pragma unroll
    for (int tt = 0; tt < MAXT; tt++) {
        if (tt < nslots) {
            int jt = wave + tt * 8;
            int c = tilec[jt];
            const unsigned short* qa = &qloc[c][m][q * 8];
            bf16x8 a0 = *(const bf16x8*)qa;
            bf16x8 a1 = *(const bf16x8*)(qa + 32);
            bool pf = (tt + 1 < nslots);
            int jbN = (wave + (tt + 1) * 8) * 64;
            if (pf) {                                  // issue half of next slot's K before MFMAs
#pragma unroll
                for (int nb = 0; nb < 2; nb++) {
                    int j = jbN + nb * 16 + m;
                    const unsigned short* kb = &KbB[(size_t)j * 64 + q * 8];
                    kB[nb * 2]     = *(const bf16x8*)kb;
                    kB[nb * 2 + 1] = *(const bf16x8*)(kb + 32);
                }
            }
            __builtin_amdgcn_s_setprio(1);
#pragma unroll
            for (int nb = 0; nb < 4; nb++) {
                f32x4 acc = {0.f, 0.f, 0.f, 0.f};
                acc = __builtin_amdgcn_mfma_f32_16x16x32_bf16(a0, kA[nb * 2], acc, 0, 0, 0);
                acc = __builtin_amdgcn_mfma_f32_16x16x32_bf16(a1, kA[nb * 2 + 1], acc, 0, 0, 0);
                int mj = mjA[nb];
#pragma unroll
                for (int g = 0; g < 4; g++) {
                    float sv;
                    if (mj == 2)             sv = -INFINITY;      // padding slot
                    else if (mrow4[g] && mj) sv = acc[g] * 0.125f;
                    else                     sv = -1e30f;         // reference's masked value
                    sarr[tt][nb][g] = sv;
                    lmax[g] = fmaxf(lmax[g], sv);
                }
            }
            __builtin_amdgcn_s_setprio(0);
            if (pf) {                                  // rotate prefetched half in, load rest
#pragma unroll
                for (int i = 0; i < 4; i++) kA[i] = kB[i];
#pragma unroll
                for (int nb = 2; nb < 4; nb++) {
                    int j = jbN + nb * 16 + m;
                    const unsigned short* kb = &KbB[(size_t)j * 64 + q * 8];
                    kA[nb * 2]     = *(const bf16x8*)kb;
                    kA[nb * 2 + 1] = *(const bf16x8*)(kb + 32);
                }
#pragma unroll
                for (int nb = 0; nb < 4; nb++) mjA[nb] = maskPB[jbN + nb * 16 + m];
            }
        }
    }
#pragma unroll
    for (int g = 0; g < 4; g++) {
        float v = lmax[g];
#pragma unroll
        for (int o = 1; o < 16; o <<= 1) v = fmaxf(v, __shfl_xor(v, o));
        lmax[g] = v;
    }
    if (m == 0) {
#pragma unroll
        for (int g = 0; g < 4; g++) wred[wave][q * 4 + g] = lmax[g];
    }
    __syncthreads();   // qloc dead from here

    // ---- phase 2: exp in regs, single P write into S, row sums (normalization deferred)
    float mx4[4], lsum[4] = {0.f, 0.f, 0.f, 0.f};
#pragma unroll
    for (int g = 0; g < 4; g++) {
        int i = q * 4 + g;
        float v = wred[0][i];
#pragma unroll
        for (int w2 = 1; w2 < 8; w2++) v = fmaxf(v, wred[w2][i]);
        mx4[g] = v;
    }
#pragma unroll
    for (int tt = 0; tt < MAXT; tt++) {
        int jt = wave + tt * 8;
        if (jt < tiles) {                              // wave-uniform skip
            int jb = jt * 64;
#pragma unroll
            for (int nb = 0; nb < 4; nb++) {
                int j = jb + nb * 16 + m;
#pragma unroll
                for (int g = 0; g < 4; g++) {
                    float p = __expf(sarr[tt][nb][g] - mx4[g]);   // -inf -> 0
                    lsum[g] += p;
                    S[q * 4 + g][j] = f2bf(p);
                }
            }
        }
    }
#pragma unroll
    for (int g = 0; g < 4; g++) {
        float v = lsum[g];
#pragma unroll
        for (int o = 1; o < 16; o <<= 1) v += __shfl_xor(v, o);
        lsum[g] = v;
    }
    if (m == 0) {
#pragma unroll
        for (int g = 0; g < 4; g++) wsum[wave][q * 4 + g] = lsum[g];
    }
    __syncthreads();

    // ---- phase 3: per-class PV into u; wave = (kw, c-half); dynamic class split;
    //      2-deep V prefetch (global, ~200cyc) + 1-deep S prefetch (LDS) carried across classes.
    {
        int kw = wave & 3, chalf = wave >> 2;
        int db = kw * 16;
        int nT2 = cstart[5];
        int sc = 1, best = 0x7fffffff;
#pragma unroll
        for (int c = 1; c <= 4; c++) {
            int d = 2 * cstart[c] - nT2;
            d = d < 0 ? -d : d;
            if (d < best) { best = d; sc = c; }
        }
        int cb = chalf ? sc : 0, ce = chalf ? 5 : sc;
        int t0 = cstart[cb] >> 6, tEnd = cstart[ce] >> 6;
        const unsigned short* Srow = &S[m][q * 8];
        const unsigned short* Vrow = &VtB[(size_t)(db + m) * NP + q * 8];
        bf16x8 a0 = {}, a1 = {};          // S of tile tcur
        bf16x8 b0 = {}, b1 = {};          // V of tile tcur
        bf16x8 vn0 = {}, vn1 = {};        // V of tile tcur+1 (2-deep stage)
        if (t0 < tEnd) {
            int jb = t0 * 64;
            a0 = *(const bf16x8*)&Srow[jb];  a1 = *(const bf16x8*)&Srow[jb + 32];
            b0 = *(const bf16x8*)&Vrow[jb];  b1 = *(const bf16x8*)&Vrow[jb + 32];
        }
        if (t0 + 1 < tEnd) {
            int jb = (t0 + 1) * 64;
            vn0 = *(const bf16x8*)&Vrow[jb];  vn1 = *(const bf16x8*)&Vrow[jb + 32];
        }
        int tcur = t0;
        for (int c = cb; c < ce; c++) {
            int ct1 = cstart[c + 1] >> 6;
            f32x4 ae = {0.f, 0.f, 0.f, 0.f};
            f32x4 ao = {0.f, 0.f, 0.f, 0.f};
            while (tcur < ct1) {
                bf16x8 ca0 = a0, ca1 = a1, cb0 = b0, cb1 = b1;
                int tn = tcur + 1, tn2 = tcur + 2;
                if (tn < tEnd) {             // S 1-deep; V rotates from the 2-deep stage
                    int jb = tn * 64;
                    a0 = *(const bf16x8*)&Srow[jb];  a1 = *(const bf16x8*)&Srow[jb + 32];
                    b0 = vn0; b1 = vn1;
                }
                if (tn2 < tEnd) {            // issue V for tile tcur+2 (crosses class boundaries)
                    int jb = tn2 * 64;
                    vn0 = *(const bf16x8*)&Vrow[jb];  vn1 = *(const bf16x8*)&Vrow[jb + 32];
                }
                __builtin_amdgcn_s_setprio(1);
                ae = __builtin_amdgcn_mfma_f32_16x16x32_bf16(ca0, cb0, ae, 0, 0, 0);
                ao = __builtin_amdgcn_mfma_f32_16x16x32_bf16(ca1, cb1, ao, 0, 0, 0);
                __builtin_amdgcn_s_setprio(0);
                tcur++;
            }
#pragma unroll
            for (int g = 0; g < 4; g++)
                u[c][q * 4 + g][db + m] = f2bf(ae[g] + ao[g]);
        }
    }
    __syncthreads();   // S dead from here; pbuf region reusable

    // ---- phase 4: out = (sum_c u[c] . W2m[cls(r,c)]); class W-loads batched before MFMAs
    {
        int kw = wave & 3, p = wave >> 2;
        int cA = p ? 3 : 0, cB = p ? 4 : 1, cC = 2;         // cC only used when !p
        size_t woff = (size_t)(kw * 16 + m) * 64 + q * 8;
        const unsigned short* wA = W2bt + (((size_t)clsOf(r, cA) * NH + h) << 12) + woff;
        const unsigned short* wB = W2bt + (((size_t)clsOf(r, cB) * NH + h) << 12) + woff;
        bf16x8 bA0 = *(const bf16x8*)wA, bA1 = *(const bf16x8*)(wA + 32);
        bf16x8 bB0 = *(const bf16x8*)wB, bB1 = *(const bf16x8*)(wB + 32);
        bf16x8 bC0 = {}, bC1 = {};
        if (!p) {
            const unsigned short* wC = W2bt + (((size_t)clsOf(r, cC) * NH + h) << 12) + woff;
            bC0 = *(const bf16x8*)wC; bC1 = *(const bf16x8*)(wC + 32);
        }
        f32x4 acc = {0.f, 0.f, 0.f, 0.f};
        {
            const unsigned short* ua = &u[cA][m][q * 8];
            bf16x8 a0 = *(const bf16x8*)ua;
            bf16x8 a1 = *(const bf16x8*)(ua + 32);
            acc = __builtin_amdgcn_mfma_f32_16x16x32_bf16(a0, bA0, acc, 0, 0, 0);
            acc = __builtin_amdgcn_mfma_f32_16x16x32_bf16(a1, bA1, acc, 0, 0, 0);
        }
        {
            const unsigned short* ua = &u[cB][m][q * 8];
            bf16x8 a0 = *(const bf16x8*)ua;
            bf16x8 a1 = *(const bf16x8*)(ua + 32);
            acc = __builtin_amdgcn_mfma_f32_16x16x32_bf16(a0, bB0, acc, 0, 0, 0);
            acc = __builtin_amdgcn_mfma_f32_16x16x32_bf16(a1, bB1, acc, 0, 0, 0);
        }
        if (!p) {
            const unsigned short* ua = &u[cC][m][q * 8];
            bf16x8 a0 = *(const bf16x8*)ua;
            bf16x8 a1 = *(const bf16x8*)(ua + 32);
            acc = __builtin_amdgcn_mfma_f32_16x16x32_bf16(a0, bC0, acc, 0, 0, 0);
            acc = __builtin_amdgcn_mfma_f32_16x16x32_bf16(a1, bC1, acc, 0, 0, 0);
        }
#pragma unroll
        for (int g = 0; g < 4; g++)
            pbuf[p][q * 4 + g][kw * 16 + m] = acc[g];
    }
    __syncthreads();

    // ---- epilogue: combine halves, normalize, store
    for (int idx = tid; idx < 16 * 64; idx += 512) {
        int i = idx >> 6, k = idx & 63;
        int tok = toki[i];
        if (tok >= 0) {
            float s = wsum[0][i] + wsum[1][i] + wsum[2][i] + wsum[3][i]
                    + wsum[4][i] + wsum[5][i] + wsum[6][i] + wsum[7][i];
            float v = pbuf[0][i][k] + pbuf[1][i][k];
            out[((size_t)b * NN + tok) * (NH * DKK) + h * DKK + k] = v / s;
        }
    }
}

// ---------------------------------------------------------------- launch
extern "C" void kernel_launch(void* const* d_in, const int* in_sizes, int n_in,
                              void* d_out, int out_size, void* d_ws, size_t ws_size,
                              hipStream_t stream)
{
    const float* qr  = (const float*)d_in[0];
    const float* kr  = (const float*)d_in[1];
    const float* vr  = (const float*)d_in[2];
    const void* bsr  = d_in[3];
    const void* mkr  = d_in[4];
    const float* lr  = (const float*)d_in[5];
    const float* w1r = (const float*)d_in[6];
    const float* a1r = (const float*)d_in[7];
    const float* w2r = (const float*)d_in[8];
    const float* a2r = (const float*)d_in[9];
    float* out = (float*)d_out;

    char* w = (char*)d_ws;
    int* maskI    = (int*)w;
    int* perm     = maskI + BQ * NN;
    int* rowc     = perm + BQ * NP;
    int* startPad = rowc + BQ * NP;
    int* maskP    = startPad + 12;
    unsigned short* W1bt = (unsigned short*)(w + 65536);
    unsigned short* W2bt = W1bt + (size_t)NCLS * NH * 4096;
    unsigned short* Qb   = (unsigned short*)(w + 2359296);
    unsigned short* Kb   = Qb + (size_t)BQ * NH * NP * 64;
    unsigned short* Vt   = Kb + (size_t)BQ * NH * NP * 64;           // [b][h][d][ip]
    unsigned short* Lt   = (unsigned short*)(w + 10616832);
    unsigned short* Xc   = (unsigned short*)(w + 26345472);          // total ~32.6 MB

    hipLaunchKernelGGL(k_prep, dim3(960 + 96 + 1), dim3(256), 0, stream,
                       lr, Lt, qr, kr, vr, Xc,
                       bsr, mkr, maskI, perm, rowc, startPad, maskP);
    hipLaunchKernelGGL(k_proj, dim3(960 + 2 * NCLS * NH), dim3(256), 0, stream,
                       Xc, Lt, perm, rowc, startPad, Qb, Kb, Vt,
                       w1r, w2r, a1r, a2r, W1bt, W2bt);
    hipLaunchKernelGGL(k_attn, dim3(8 * 2 * 80), dim3(512), 0, stream,
                       Qb, Kb, Vt, W1bt, W2bt, perm, rowc, startPad, maskI, maskP, out);
}